// Round 13
// baseline (214.477 us; speedup 1.0000x reference)
//
#include <hip/hip_runtime.h>

typedef unsigned short u16;
typedef unsigned int u32;
typedef __bf16 bf16x8 __attribute__((ext_vector_type(8)));
typedef short s16x4 __attribute__((ext_vector_type(4)));
typedef float f32x4 __attribute__((ext_vector_type(4)));

#define CC 768
#define TT 2560
#define NH 12
#define HD 64
#define KDIM 768

// 1/sqrt(64) * log2(e) -- folded into q in the QKV GEMM epilogue
#define QSCALE 0.18033688011112042f

__device__ __forceinline__ u16 f2bf(float f) {
  u32 u = __builtin_bit_cast(u32, f);
  u32 r = u + 0x7fffu + ((u >> 16) & 1u);
  return (u16)(r >> 16);
}

#if __has_builtin(__builtin_amdgcn_mfma_f32_16x16x16bf16_1k)
__device__ __forceinline__ f32x4 mfma16b(s16x4 a, s16x4 b, f32x4 c) {
  return __builtin_amdgcn_mfma_f32_16x16x16bf16_1k(a, b, c, 0, 0, 0);
}
#else
__device__ __forceinline__ f32x4 mfma16b(s16x4 a, s16x4 b, f32x4 c) {
  f32x4 d;
  asm("v_mfma_f32_16x16x16_bf16 %0, %1, %2, %3\n\ts_nop 7\n\ts_nop 7"
      : "=v"(d) : "v"(a), "v"(b), "v"(c));
  return d;
}
#endif

// ---------------- fused fp32 -> bf16 converts (1 launch) ----------------
__global__ void convall(const float* __restrict__ x,
                        const float* __restrict__ Wq, const float* __restrict__ Wk,
                        const float* __restrict__ Wv, const float* __restrict__ Wp,
                        u16* __restrict__ xb, u16* __restrict__ wqb, u16* __restrict__ wkb,
                        u16* __restrict__ wvb, u16* __restrict__ wpb,
                        int nx4, int nw4) {
  int z = blockIdx.y;
  const float* in; u16* out; int n4;
  switch (z) {
    case 0: in = x;  out = xb;  n4 = nx4; break;
    case 1: in = Wq; out = wqb; n4 = nw4; break;
    case 2: in = Wk; out = wkb; n4 = nw4; break;
    case 3: in = Wv; out = wvb; n4 = nw4; break;
    default: in = Wp; out = wpb; n4 = nw4; break;
  }
  int i = blockIdx.x * blockDim.x + threadIdx.x;
  if (i >= n4) return;
  float4 v = ((const float4*)in)[i];
  ushort4 o;
  o.x = f2bf(v.x); o.y = f2bf(v.y); o.z = f2bf(v.z); o.w = f2bf(v.w);
  ((ushort4*)out)[i] = o;
}

// ---------------- QKV projection GEMM: 128x128 tile (r10, validated) -------
// XCD-aware swizzle (r10/r11 confirmed: FETCH 55->33MB, x panel L2-resident
// per XCD). NO register additions: r7 (launch_bounds), r9 (tile-halve), r11
// (reg-dbuf) all failed -- zero register headroom here.
// z=0 -> q*QSCALE [B,H,T,64]   (transposed acc: vectorized ushort4 stores)
// z=1 -> k grouped [B,H, T/16, 2(kc), 16(key%16), 32(d%32)]  (transposed acc)
// z=2 -> v grouped [B,H, T/16, 64(d), 16(key%16)]            (normal acc)
__global__ __launch_bounds__(256) void gemm_qkv(
    const u16* __restrict__ xb,
    const u16* __restrict__ wqb, const u16* __restrict__ wkb, const u16* __restrict__ wvb,
    const float* __restrict__ bq, const float* __restrict__ bk, const float* __restrict__ bv,
    u16* __restrict__ qo, u16* __restrict__ ko, u16* __restrict__ vo)
{
  __shared__ __align__(16) u16 lds_a[128 * 72];
  __shared__ __align__(16) u16 lds_b[128 * 72];
  // decode swizzled block id: c=XCD, y%8==c for all blocks of a y-panel
  int g = blockIdx.x;
  int c = g & 7;          // XCD (round-robin dispatch heuristic)
  int t = g >> 3;         // 0..89
  int yhi = t % 5;
  int j = t / 5;          // 0..17 -> (x,z)
  int y = yhi * 8 + c;    // 0..39 (m-panel); all (x,z) of this y on XCD c
  int xg = j % 6;
  int z = j / 6;
  const u16* W = (z == 0) ? wqb : (z == 1 ? wkb : wvb);
  const float* bias = (z == 0) ? bq : (z == 1 ? bk : bv);
  int n0 = xg * 128;
  int m0 = y * 128;
  int tid = threadIdx.x;
  int lane = tid & 63, wv_ = tid >> 6;
  int wm = wv_ & 1, wn = wv_ >> 1;
  int mcol = lane & 15, quad = lane >> 4;
  int chunk = tid & 7, rbase = tid >> 3;

  f32x4 acc[4][4] = {};

  for (int k0 = 0; k0 < KDIM; k0 += 64) {
    __syncthreads();
#pragma unroll
    for (int r = 0; r < 4; ++r) {
      int row = rbase + r * 32;
      *(uint4*)&lds_a[row * 72 + chunk * 8] =
          *(const uint4*)&xb[(size_t)(m0 + row) * KDIM + k0 + chunk * 8];
      *(uint4*)&lds_b[row * 72 + chunk * 8] =
          *(const uint4*)&W[(size_t)(n0 + row) * KDIM + k0 + chunk * 8];
    }
    __syncthreads();
#pragma unroll
    for (int kc = 0; kc < 2; ++kc) {
      bf16x8 af[4], bfr[4];
#pragma unroll
      for (int i = 0; i < 4; i++)
        af[i] = *(const bf16x8*)&lds_a[(wm * 64 + i * 16 + mcol) * 72 + kc * 32 + quad * 8];
#pragma unroll
      for (int i = 0; i < 4; i++)
        bfr[i] = *(const bf16x8*)&lds_b[(wn * 64 + i * 16 + mcol) * 72 + kc * 32 + quad * 8];
      if (z == 2) {
#pragma unroll
        for (int i = 0; i < 4; i++)
#pragma unroll
          for (int j2 = 0; j2 < 4; j2++)
            acc[i][j2] = __builtin_amdgcn_mfma_f32_16x16x32_bf16(af[i], bfr[j2], acc[i][j2], 0, 0, 0);
      } else {
        // transposed: m-dim = W channel, n-dim = token
#pragma unroll
        for (int i = 0; i < 4; i++)
#pragma unroll
          for (int j2 = 0; j2 < 4; j2++)
            acc[i][j2] = __builtin_amdgcn_mfma_f32_16x16x32_bf16(bfr[j2], af[i], acc[i][j2], 0, 0, 0);
      }
    }
  }

  if (z == 2) {
    // normal orientation: lane holds 4 consecutive tokens, fixed channel
#pragma unroll
    for (int i = 0; i < 4; i++) {
      int rowb = m0 + wm * 64 + i * 16 + quad * 4;
      int b = rowb / TT;
      int tt0 = rowb - b * TT;     // key token, multiple of 4
#pragma unroll
      for (int j2 = 0; j2 < 4; j2++) {
        int col = n0 + wn * 64 + j2 * 16 + mcol;
        int h = col >> 6, d = col & 63;
        float bb_ = bias[col];
        size_t bhoff = (size_t)(b * NH + h) * (TT * HD);
        ushort4 pk;
        pk.x = f2bf(acc[i][j2][0] + bb_);
        pk.y = f2bf(acc[i][j2][1] + bb_);
        pk.z = f2bf(acc[i][j2][2] + bb_);
        pk.w = f2bf(acc[i][j2][3] + bb_);
        *(ushort4*)&vo[bhoff + (size_t)(tt0 >> 4) * 1024 + d * 16 + (tt0 & 15)] = pk;
      }
    }
  } else {
    // transposed: lane holds 4 consecutive channels, fixed token
    u16* dst = (z == 0) ? qo : ko;
    float scale = (z == 0) ? QSCALE : 1.0f;
#pragma unroll
    for (int i = 0; i < 4; i++) {
      int token = m0 + wm * 64 + i * 16 + mcol;
      int b = token / TT;
      int tt = token - b * TT;
#pragma unroll
      for (int j2 = 0; j2 < 4; j2++) {
        int ch0 = n0 + wn * 64 + j2 * 16 + quad * 4;
        int h = ch0 >> 6, d4 = ch0 & 63;
        float4 bb4 = *(const float4*)&bias[ch0];
        size_t bhoff = (size_t)(b * NH + h) * (TT * HD);
        ushort4 pk;
        pk.x = f2bf((acc[i][j2][0] + bb4.x) * scale);
        pk.y = f2bf((acc[i][j2][1] + bb4.y) * scale);
        pk.z = f2bf((acc[i][j2][2] + bb4.z) * scale);
        pk.w = f2bf((acc[i][j2][3] + bb4.w) * scale);
        if (z == 0) {
          *(ushort4*)&dst[bhoff + (size_t)tt * HD + d4] = pk;
        } else {
          *(ushort4*)&dst[bhoff + (size_t)(tt >> 4) * 1024 + (d4 >> 5) * 512 +
                          (tt & 15) * 32 + (d4 & 31)] = pk;
        }
      }
    }
  }
}

// ------- fused masked attention: 4 strips/wave, 2-way K-split per block ------
// Depth-2 rotating-register prefetch + s_setprio (validated: 47.8us, r8).
struct Strip {
  bf16x8 qf0, qf1;
  f32x4 o0, o1, o2, o3;
  f32x4 racc;   // ones-row MFMA accumulator: racc[0] = softmax denominator
};

__device__ __forceinline__ void strip_step(
    Strip& S, bf16x8 kf0, bf16x8 kf1,
    s16x4 vf0, s16x4 vf1, s16x4 vf2, s16x4 vf3,
    bool maskg, int mcol, int quad)
{
  f32x4 st = {0.f, 0.f, 0.f, 0.f};
  __builtin_amdgcn_s_setprio(1);
  st = __builtin_amdgcn_mfma_f32_16x16x32_bf16(kf0, S.qf0, st, 0, 0, 0);
  st = __builtin_amdgcn_mfma_f32_16x16x32_bf16(kf1, S.qf1, st, 0, 0, 0);
  __builtin_amdgcn_s_setprio(0);
  float p0 = __builtin_amdgcn_exp2f(st[0]);
  float p1 = __builtin_amdgcn_exp2f(st[1]);
  float p2 = __builtin_amdgcn_exp2f(st[2]);
  float p3 = __builtin_amdgcn_exp2f(st[3]);
  if (maskg) {
    int j0 = quad * 4;
    p0 = (j0 + 0 > mcol) ? 0.f : p0;
    p1 = (j0 + 1 > mcol) ? 0.f : p1;
    p2 = (j0 + 2 > mcol) ? 0.f : p2;
    p3 = (j0 + 3 > mcol) ? 0.f : p3;
  }
  // truncate to bf16 (no rounding add): bias cancels against rsum
  uint2 pk;
  pk.x = __builtin_amdgcn_perm(__builtin_bit_cast(u32, p1),
                               __builtin_bit_cast(u32, p0), 0x07060302u);
  pk.y = __builtin_amdgcn_perm(__builtin_bit_cast(u32, p3),
                               __builtin_bit_cast(u32, p2), 0x07060302u);
  s16x4 pf = __builtin_bit_cast(s16x4, pk);
  const s16x4 ones = {0x3F80, 0x3F80, 0x3F80, 0x3F80};  // bf16 1.0 x4
  __builtin_amdgcn_s_setprio(1);
  S.racc = mfma16b(ones, pf, S.racc);
  S.o0 = mfma16b(vf0, pf, S.o0);
  S.o1 = mfma16b(vf1, pf, S.o1);
  S.o2 = mfma16b(vf2, pf, S.o2);
  S.o3 = mfma16b(vf3, pf, S.o3);
  __builtin_amdgcn_s_setprio(0);
}

#define OSTR 68   // padded f32 row stride for combine staging (bank stagger)

__global__ __launch_bounds__(128) void attn(
    const u16* __restrict__ q, const u16* __restrict__ kg,
    const u16* __restrict__ vg, u16* __restrict__ y)
{
  __shared__ float lds_o[4][16 * OSTR];
  __shared__ float lds_r[64];

  int tid = threadIdx.x;
  int lane = tid & 63, w = tid >> 6;   // w = K-half owner
  int mcol = lane & 15, quad = lane >> 4;
  int gid = blockIdx.x;
  int c = gid & 7;              // XCD (round-robin dispatch heuristic)
  int idx = gid >> 3;           // 0..119
  int sub = idx / 40;           // 0..2  -> 3 bh per XCD (K/V resident in L2)
  int s = idx - sub * 40;       // 0..39
  int bh = c * 3 + sub;
  int hb = s >> 3;              // 0..4  (512-row span)
  int r = s & 7;                // light local strip; heavy local = 7-r
  int b = bh / NH, h = bh - b * NH;
  const u16* qp = q + (size_t)bh * TT * HD;
  const u16* kp = kg + (size_t)bh * TT * HD;
  const u16* vp = vg + (size_t)bh * TT * HD;

  int base = hb * 512;
  int rh = 7 - r;
  int qr[4];
  qr[0] = base + r * 16;              // L1 (half 0 of 256-tile)
  qr[1] = base + 128 + rh * 16;       // H1 (half 1)
  qr[2] = base + 256 + r * 16;        // L2
  qr[3] = base + 384 + rh * 16;       // H2

  Strip S[4];
#pragma unroll
  for (int i = 0; i < 4; ++i) {
    S[i].qf0 = *(const bf16x8*)&qp[(size_t)(qr[i] + mcol) * HD + quad * 8];
    S[i].qf1 = *(const bf16x8*)&qp[(size_t)(qr[i] + mcol) * HD + 32 + quad * 8];
    S[i].o0 = {0.f, 0.f, 0.f, 0.f};
    S[i].o1 = {0.f, 0.f, 0.f, 0.f};
    S[i].o2 = {0.f, 0.f, 0.f, 0.f};
    S[i].o3 = {0.f, 0.f, 0.f, 0.f};
    S[i].racc = {0.f, 0.f, 0.f, 0.f};
  }

  int koff = mcol * 32 + quad * 8;  // u16 offset in K group (b128, coalesced)
  int voff = mcol * 16 + quad * 4;  // u16 offset in V df-slab (b64, coalesced)

  for (int kt = w * 10; kt < w * 10 + 10; ++kt) {
    const u16* ktb = kp + kt * (128 * HD);
    const u16* vtb = vp + kt * (128 * HD);
    if ((kt & 1) == 0) {
      // even tile: heavy strips full 8 groups; light strips groups 0..r
      // depth-2 rotating-register prefetch (~two groups of MFMA cover)
      bf16x8 ck0 = *(const bf16x8*)&ktb[koff];
      bf16x8 ck1 = *(const bf16x8*)&ktb[512 + koff];
      s16x4 cv0 = *(const s16x4*)&vtb[0 * 256 + voff];
      s16x4 cv1 = *(const s16x4*)&vtb[1 * 256 + voff];
      s16x4 cv2 = *(const s16x4*)&vtb[2 * 256 + voff];
      s16x4 cv3 = *(const s16x4*)&vtb[3 * 256 + voff];
      bf16x8 nk0 = *(const bf16x8*)&ktb[1024 + koff];
      bf16x8 nk1 = *(const bf16x8*)&ktb[1024 + 512 + koff];
      s16x4 nv0 = *(const s16x4*)&vtb[1024 + 0 * 256 + voff];
      s16x4 nv1 = *(const s16x4*)&vtb[1024 + 1 * 256 + voff];
      s16x4 nv2 = *(const s16x4*)&vtb[1024 + 2 * 256 + voff];
      s16x4 nv3 = *(const s16x4*)&vtb[1024 + 3 * 256 + voff];
#pragma unroll
      for (int g = 0; g < 8; ++g) {
        bf16x8 pk0, pk1; s16x4 pv0, pv1, pv2, pv3;
        if (g < 6) {
          const u16* kn = ktb + (g + 2) * 1024;
          const u16* vn = vtb + (g + 2) * 1024;
          pk0 = *(const bf16x8*)&kn[koff];
          pk1 = *(const bf16x8*)&kn[512 + koff];
          pv0 = *(const s16x4*)&vn[0 * 256 + voff];
          pv1 = *(const s16x4*)&vn[1 * 256 + voff];
          pv2 = *(const s16x4*)&vn[2 * 256 + voff];
          pv3 = *(const s16x4*)&vn[3 * 256 + voff];
        }
        strip_step(S[1], ck0, ck1, cv0, cv1, cv2, cv3, false, mcol, quad);
        strip_step(S[3], ck0, ck1, cv0, cv1, cv2, cv3, false, mcol, quad);
        if (g <= r) {
          bool mg = (g == r);
          strip_step(S[0], ck0, ck1, cv0, cv1, cv2, cv3, mg, mcol, quad);
          strip_step(S[2], ck0, ck1, cv0, cv1, cv2, cv3, mg, mcol, quad);
        }
        if (g < 7) {
          ck0 = nk0; ck1 = nk1;
          cv0 = nv0; cv1 = nv1; cv2 = nv2; cv3 = nv3;
        }
        if (g < 6) {
          nk0 = pk0; nk1 = pk1;
          nv0 = pv0; nv1 = pv1; nv2 = pv2; nv3 = pv3;
        }
      }
    } else {
      // odd tile: heavy strips groups 0..rh (partial at rh); light strips skip
      // runtime-bound loop -> depth-1 rotating prefetch (clamped last load)
      bf16x8 kf0 = *(const bf16x8*)&ktb[koff];
      bf16x8 kf1 = *(const bf16x8*)&ktb[512 + koff];
      s16x4 vf0 = *(const s16x4*)&vtb[0 * 256 + voff];
      s16x4 vf1 = *(const s16x4*)&vtb[1 * 256 + voff];
      s16x4 vf2 = *(const s16x4*)&vtb[2 * 256 + voff];
      s16x4 vf3 = *(const s16x4*)&vtb[3 * 256 + voff];
      for (int g = 0; g <= rh; ++g) {
        int gn = (g < rh) ? g + 1 : g;
        const u16* kn = ktb + gn * 1024;
        const u16* vn = vtb + gn * 1024;
        bf16x8 nk0 = *(const bf16x8*)&kn[koff];
        bf16x8 nk1 = *(const bf16x8*)&kn[512 + koff];
        s16x4 nv0 = *(const s16x4*)&vn[0 * 256 + voff];
        s16x4 nv1 = *(const s16x4*)&vn[1 * 256 + voff];
        s16x4 nv2 = *(const s16x4*)&vn[2 * 256 + voff];
        s16x4 nv3 = *(const s16x4*)&vn[3 * 256 + voff];
        bool mg = (g == rh);
        strip_step(S[1], kf0, kf1, vf0, vf1, vf2, vf3, mg, mcol, quad);
        strip_step(S[3], kf0, kf1, vf0, vf1, vf2, vf3, mg, mcol, quad);
        kf0 = nk0; kf1 = nk1;
        vf0 = nv0; vf1 = nv1; vf2 = nv2; vf3 = nv3;
      }
    }
  }

  // ---- combine the two K-halves through LDS (partials are additive, m=0) ----
  if (w == 1) {
#pragma unroll
    for (int i = 0; i < 4; ++i) {
      f32x4 oo[4] = {S[i].o0, S[i].o1, S[i].o2, S[i].o3};
#pragma unroll
      for (int df = 0; df < 4; ++df)
        *(f32x4*)&lds_o[i][mcol * OSTR + df * 16 + quad * 4] = oo[df];
      if (quad == 0) lds_r[i * 16 + mcol] = S[i].racc[0];
    }
  }
  __syncthreads();
  if (w == 0) {
#pragma unroll
    for (int i = 0; i < 4; ++i) {
      float denom = S[i].racc[0] + lds_r[i * 16 + mcol];
      float inv = 1.0f / denom;
      f32x4 oo[4] = {S[i].o0, S[i].o1, S[i].o2, S[i].o3};
      size_t yrow = ((size_t)(b * TT + qr[i] + mcol)) * CC + h * HD;
#pragma unroll
      for (int df = 0; df < 4; ++df) {
        f32x4 other = *(const f32x4*)&lds_o[i][mcol * OSTR + df * 16 + quad * 4];
        ushort4 pk;
        pk.x = f2bf((oo[df][0] + other[0]) * inv);
        pk.y = f2bf((oo[df][1] + other[1]) * inv);
        pk.z = f2bf((oo[df][2] + other[2]) * inv);
        pk.w = f2bf((oo[df][3] + other[3]) * inv);
        *(ushort4*)&y[yrow + df * 16 + quad * 4] = pk;
      }
    }
  }
}

// ------- output projection GEMM: 64x128 tile, 480 blocks ---------
// XCD swizzle (r11, neutral but harmless). NEW (r13): register double-
// buffered staging -- unlike gemm_qkv (zero headroom, r11 spilled), this
// kernel's acc is only 32 AGPR + ~100 VGPR, so the 6 in-flight uint4s
// (+24 VGPR -> ~156 unified) fit without spilling. Same attn-r6 mechanism:
// next k-step's fragments issued after the compute barrier, consumed at the
// next LDS write; L2 latency hides under the MFMA phase.
// transposed epilogue: acc m-dim = channel, n-dim = token -> float4 stores
__global__ __launch_bounds__(256) void gemm_out(
    const u16* __restrict__ yb, const u16* __restrict__ wpb,
    const float* __restrict__ bp, float* __restrict__ out)
{
  __shared__ __align__(16) u16 lds_a[64 * 72];    // y tokens
  __shared__ __align__(16) u16 lds_b[128 * 72];   // Wp channels
  int g = blockIdx.x;
  int c = g & 7;          // XCD
  int t = g >> 3;         // 0..59
  int y = (t % 10) * 8 + c;   // 0..79 m-panel; all x of this y on XCD c
  int xg = t / 10;        // 0..5
  int n0 = xg * 128;
  int m0 = y * 64;
  int tid = threadIdx.x;
  int lane = tid & 63, wv_ = tid >> 6;
  int wm = wv_ & 1, wn = wv_ >> 1;
  int mcol = lane & 15, quad = lane >> 4;
  int chunk = tid & 7, rbase = tid >> 3;

  f32x4 acc[2][4] = {};

  // prologue: stage k0=0 fragments into registers
  uint4 ra[2], rb[4];
#pragma unroll
  for (int r = 0; r < 2; ++r)
    ra[r] = *(const uint4*)&yb[(size_t)(m0 + rbase + r * 32) * KDIM + chunk * 8];
#pragma unroll
  for (int r = 0; r < 4; ++r)
    rb[r] = *(const uint4*)&wpb[(size_t)(n0 + rbase + r * 32) * KDIM + chunk * 8];

  for (int k0 = 0; k0 < KDIM; k0 += 64) {
    __syncthreads();
#pragma unroll
    for (int r = 0; r < 2; ++r)
      *(uint4*)&lds_a[(rbase + r * 32) * 72 + chunk * 8] = ra[r];
#pragma unroll
    for (int r = 0; r < 4; ++r)
      *(uint4*)&lds_b[(rbase + r * 32) * 72 + chunk * 8] = rb[r];
    __syncthreads();
    // issue next k-step loads (consumed at next iteration's LDS write)
    if (k0 + 64 < KDIM) {
#pragma unroll
      for (int r = 0; r < 2; ++r)
        ra[r] = *(const uint4*)&yb[(size_t)(m0 + rbase + r * 32) * KDIM + k0 + 64 + chunk * 8];
#pragma unroll
      for (int r = 0; r < 4; ++r)
        rb[r] = *(const uint4*)&wpb[(size_t)(n0 + rbase + r * 32) * KDIM + k0 + 64 + chunk * 8];
    }
#pragma unroll
    for (int kc = 0; kc < 2; ++kc) {
      bf16x8 af[2], bfr[4];
#pragma unroll
      for (int i = 0; i < 2; i++)
        af[i] = *(const bf16x8*)&lds_a[(wm * 32 + i * 16 + mcol) * 72 + kc * 32 + quad * 8];
#pragma unroll
      for (int j = 0; j < 4; j++)
        bfr[j] = *(const bf16x8*)&lds_b[(wn * 64 + j * 16 + mcol) * 72 + kc * 32 + quad * 8];
#pragma unroll
      for (int i = 0; i < 2; i++)
#pragma unroll
        for (int j = 0; j < 4; j++)
          acc[i][j] = __builtin_amdgcn_mfma_f32_16x16x32_bf16(bfr[j], af[i], acc[i][j], 0, 0, 0);
    }
  }

#pragma unroll
  for (int i = 0; i < 2; i++) {
    int token = m0 + wm * 32 + i * 16 + mcol;
#pragma unroll
    for (int j = 0; j < 4; j++) {
      int ch0 = n0 + wn * 64 + j * 16 + quad * 4;
      float4 bb4 = *(const float4*)&bp[ch0];
      float4 o4;
      o4.x = acc[i][j][0] + bb4.x;
      o4.y = acc[i][j][1] + bb4.y;
      o4.z = acc[i][j][2] + bb4.z;
      o4.w = acc[i][j][3] + bb4.w;
      *(float4*)&out[(size_t)token * CC + ch0] = o4;
    }
  }
}

extern "C" void kernel_launch(void* const* d_in, const int* in_sizes, int n_in,
                              void* d_out, int out_size, void* d_ws, size_t ws_size,
                              hipStream_t stream) {
  const float* x  = (const float*)d_in[0];
  const float* Wk = (const float*)d_in[1];
  const float* bk = (const float*)d_in[2];
  const float* Wq = (const float*)d_in[3];
  const float* bq = (const float*)d_in[4];
  const float* Wv = (const float*)d_in[5];
  const float* bv = (const float*)d_in[6];
  const float* Wp = (const float*)d_in[7];
  const float* bp = (const float*)d_in[8];
  float* out = (float*)d_out;

  char* ws = (char*)d_ws;
  size_t off = 0;
  auto alloc = [&](size_t bytes) {
    void* p = ws + off;
    off += (bytes + 255) & ~(size_t)255;
    return p;
  };
  const size_t NX = (size_t)2 * TT * CC;
  const size_t NW = (size_t)CC * CC;
  u16* xb  = (u16*)alloc(NX * 2);
  u16* wqb = (u16*)alloc(NW * 2);
  u16* wkb = (u16*)alloc(NW * 2);
  u16* wvb = (u16*)alloc(NW * 2);
  u16* wpb = (u16*)alloc(NW * 2);
  u16* qws = (u16*)alloc(NX * 2);
  u16* kws = (u16*)alloc(NX * 2);
  u16* vgw = (u16*)alloc(NX * 2);
  u16* yws = (u16*)alloc(NX * 2);

  int nx4 = (int)(NX / 4), nw4 = (int)(NW / 4);
  convall<<<dim3((nx4 + 255) / 256, 5), 256, 0, stream>>>(
      x, Wq, Wk, Wv, Wp, xb, wqb, wkb, wvb, wpb, nx4, nw4);

  gemm_qkv<<<dim3(720), 256, 0, stream>>>(xb, wqb, wkb, wvb, bq, bk, bv,
                                          qws, kws, vgw);
  attn<<<dim3(960), 128, 0, stream>>>(qws, kws, vgw, yws);
  gemm_out<<<dim3(480), 256, 0, stream>>>(yws, wpb, bp, out);
}

// Round 14
// 181.098 us; speedup vs baseline: 1.1843x; 1.1843x over previous
//
#include <hip/hip_runtime.h>

typedef unsigned short u16;
typedef unsigned int u32;
typedef __bf16 bf16x8 __attribute__((ext_vector_type(8)));
typedef short s16x4 __attribute__((ext_vector_type(4)));
typedef float f32x4 __attribute__((ext_vector_type(4)));

#define CC 768
#define TT 2560
#define NH 12
#define HD 64
#define KDIM 768

// 1/sqrt(64) * log2(e) -- folded into q in the QKV GEMM epilogue
#define QSCALE 0.18033688011112042f

__device__ __forceinline__ u16 f2bf(float f) {
  u32 u = __builtin_bit_cast(u32, f);
  u32 r = u + 0x7fffu + ((u >> 16) & 1u);
  return (u16)(r >> 16);
}

#if __has_builtin(__builtin_amdgcn_mfma_f32_16x16x16bf16_1k)
__device__ __forceinline__ f32x4 mfma16b(s16x4 a, s16x4 b, f32x4 c) {
  return __builtin_amdgcn_mfma_f32_16x16x16bf16_1k(a, b, c, 0, 0, 0);
}
#else
__device__ __forceinline__ f32x4 mfma16b(s16x4 a, s16x4 b, f32x4 c) {
  f32x4 d;
  asm("v_mfma_f32_16x16x16_bf16 %0, %1, %2, %3\n\ts_nop 7\n\ts_nop 7"
      : "=v"(d) : "v"(a), "v"(b), "v"(c));
  return d;
}
#endif

// ---------------- fused fp32 -> bf16 converts (1 launch) ----------------
__global__ void convall(const float* __restrict__ x,
                        const float* __restrict__ Wq, const float* __restrict__ Wk,
                        const float* __restrict__ Wv, const float* __restrict__ Wp,
                        u16* __restrict__ xb, u16* __restrict__ wqb, u16* __restrict__ wkb,
                        u16* __restrict__ wvb, u16* __restrict__ wpb,
                        int nx4, int nw4) {
  int z = blockIdx.y;
  const float* in; u16* out; int n4;
  switch (z) {
    case 0: in = x;  out = xb;  n4 = nx4; break;
    case 1: in = Wq; out = wqb; n4 = nw4; break;
    case 2: in = Wk; out = wkb; n4 = nw4; break;
    case 3: in = Wv; out = wvb; n4 = nw4; break;
    default: in = Wp; out = wpb; n4 = nw4; break;
  }
  int i = blockIdx.x * blockDim.x + threadIdx.x;
  if (i >= n4) return;
  float4 v = ((const float4*)in)[i];
  ushort4 o;
  o.x = f2bf(v.x); o.y = f2bf(v.y); o.z = f2bf(v.z); o.w = f2bf(v.w);
  ((ushort4*)out)[i] = o;
}

// ---------------- QKV projection GEMM: 128x128 tile (r10, validated) -------
// XCD-aware swizzle (r10/r11 confirmed: FETCH 55->33MB, x panel L2-resident
// per XCD). NO register additions: r7 (launch_bounds), r9 (tile-halve), r11
// (reg-dbuf) all spilled -- zero register headroom; the hipcc allocator will
// not hold values live across __syncthreads()+MFMA loops in this shape.
// z=0 -> q*QSCALE [B,H,T,64]   (transposed acc: vectorized ushort4 stores)
// z=1 -> k grouped [B,H, T/16, 2(kc), 16(key%16), 32(d%32)]  (transposed acc)
// z=2 -> v grouped [B,H, T/16, 64(d), 16(key%16)]            (normal acc)
__global__ __launch_bounds__(256) void gemm_qkv(
    const u16* __restrict__ xb,
    const u16* __restrict__ wqb, const u16* __restrict__ wkb, const u16* __restrict__ wvb,
    const float* __restrict__ bq, const float* __restrict__ bk, const float* __restrict__ bv,
    u16* __restrict__ qo, u16* __restrict__ ko, u16* __restrict__ vo)
{
  __shared__ __align__(16) u16 lds_a[128 * 72];
  __shared__ __align__(16) u16 lds_b[128 * 72];
  // decode swizzled block id: c=XCD, y%8==c for all blocks of a y-panel
  int g = blockIdx.x;
  int c = g & 7;          // XCD (round-robin dispatch heuristic)
  int t = g >> 3;         // 0..89
  int yhi = t % 5;
  int j = t / 5;          // 0..17 -> (x,z)
  int y = yhi * 8 + c;    // 0..39 (m-panel); all (x,z) of this y on XCD c
  int xg = j % 6;
  int z = j / 6;
  const u16* W = (z == 0) ? wqb : (z == 1 ? wkb : wvb);
  const float* bias = (z == 0) ? bq : (z == 1 ? bk : bv);
  int n0 = xg * 128;
  int m0 = y * 128;
  int tid = threadIdx.x;
  int lane = tid & 63, wv_ = tid >> 6;
  int wm = wv_ & 1, wn = wv_ >> 1;
  int mcol = lane & 15, quad = lane >> 4;
  int chunk = tid & 7, rbase = tid >> 3;

  f32x4 acc[4][4] = {};

  for (int k0 = 0; k0 < KDIM; k0 += 64) {
    __syncthreads();
#pragma unroll
    for (int r = 0; r < 4; ++r) {
      int row = rbase + r * 32;
      *(uint4*)&lds_a[row * 72 + chunk * 8] =
          *(const uint4*)&xb[(size_t)(m0 + row) * KDIM + k0 + chunk * 8];
      *(uint4*)&lds_b[row * 72 + chunk * 8] =
          *(const uint4*)&W[(size_t)(n0 + row) * KDIM + k0 + chunk * 8];
    }
    __syncthreads();
#pragma unroll
    for (int kc = 0; kc < 2; ++kc) {
      bf16x8 af[4], bfr[4];
#pragma unroll
      for (int i = 0; i < 4; i++)
        af[i] = *(const bf16x8*)&lds_a[(wm * 64 + i * 16 + mcol) * 72 + kc * 32 + quad * 8];
#pragma unroll
      for (int i = 0; i < 4; i++)
        bfr[i] = *(const bf16x8*)&lds_b[(wn * 64 + i * 16 + mcol) * 72 + kc * 32 + quad * 8];
      if (z == 2) {
#pragma unroll
        for (int i = 0; i < 4; i++)
#pragma unroll
          for (int j2 = 0; j2 < 4; j2++)
            acc[i][j2] = __builtin_amdgcn_mfma_f32_16x16x32_bf16(af[i], bfr[j2], acc[i][j2], 0, 0, 0);
      } else {
        // transposed: m-dim = W channel, n-dim = token
#pragma unroll
        for (int i = 0; i < 4; i++)
#pragma unroll
          for (int j2 = 0; j2 < 4; j2++)
            acc[i][j2] = __builtin_amdgcn_mfma_f32_16x16x32_bf16(bfr[j2], af[i], acc[i][j2], 0, 0, 0);
      }
    }
  }

  if (z == 2) {
    // normal orientation: lane holds 4 consecutive tokens, fixed channel
#pragma unroll
    for (int i = 0; i < 4; i++) {
      int rowb = m0 + wm * 64 + i * 16 + quad * 4;
      int b = rowb / TT;
      int tt0 = rowb - b * TT;     // key token, multiple of 4
#pragma unroll
      for (int j2 = 0; j2 < 4; j2++) {
        int col = n0 + wn * 64 + j2 * 16 + mcol;
        int h = col >> 6, d = col & 63;
        float bb_ = bias[col];
        size_t bhoff = (size_t)(b * NH + h) * (TT * HD);
        ushort4 pk;
        pk.x = f2bf(acc[i][j2][0] + bb_);
        pk.y = f2bf(acc[i][j2][1] + bb_);
        pk.z = f2bf(acc[i][j2][2] + bb_);
        pk.w = f2bf(acc[i][j2][3] + bb_);
        *(ushort4*)&vo[bhoff + (size_t)(tt0 >> 4) * 1024 + d * 16 + (tt0 & 15)] = pk;
      }
    }
  } else {
    // transposed: lane holds 4 consecutive channels, fixed token
    u16* dst = (z == 0) ? qo : ko;
    float scale = (z == 0) ? QSCALE : 1.0f;
#pragma unroll
    for (int i = 0; i < 4; i++) {
      int token = m0 + wm * 64 + i * 16 + mcol;
      int b = token / TT;
      int tt = token - b * TT;
#pragma unroll
      for (int j2 = 0; j2 < 4; j2++) {
        int ch0 = n0 + wn * 64 + j2 * 16 + quad * 4;
        int h = ch0 >> 6, d4 = ch0 & 63;
        float4 bb4 = *(const float4*)&bias[ch0];
        size_t bhoff = (size_t)(b * NH + h) * (TT * HD);
        ushort4 pk;
        pk.x = f2bf((acc[i][j2][0] + bb4.x) * scale);
        pk.y = f2bf((acc[i][j2][1] + bb4.y) * scale);
        pk.z = f2bf((acc[i][j2][2] + bb4.z) * scale);
        pk.w = f2bf((acc[i][j2][3] + bb4.w) * scale);
        if (z == 0) {
          *(ushort4*)&dst[bhoff + (size_t)tt * HD + d4] = pk;
        } else {
          *(ushort4*)&dst[bhoff + (size_t)(tt >> 4) * 1024 + (d4 >> 5) * 512 +
                          (tt & 15) * 32 + (d4 & 31)] = pk;
        }
      }
    }
  }
}

// ------- fused masked attention: 4 strips/wave, 2-way K-split per block ------
// Depth-2 rotating-register prefetch + s_setprio (validated: 47.8us, r8).
struct Strip {
  bf16x8 qf0, qf1;
  f32x4 o0, o1, o2, o3;
  f32x4 racc;   // ones-row MFMA accumulator: racc[0] = softmax denominator
};

__device__ __forceinline__ void strip_step(
    Strip& S, bf16x8 kf0, bf16x8 kf1,
    s16x4 vf0, s16x4 vf1, s16x4 vf2, s16x4 vf3,
    bool maskg, int mcol, int quad)
{
  f32x4 st = {0.f, 0.f, 0.f, 0.f};
  __builtin_amdgcn_s_setprio(1);
  st = __builtin_amdgcn_mfma_f32_16x16x32_bf16(kf0, S.qf0, st, 0, 0, 0);
  st = __builtin_amdgcn_mfma_f32_16x16x32_bf16(kf1, S.qf1, st, 0, 0, 0);
  __builtin_amdgcn_s_setprio(0);
  float p0 = __builtin_amdgcn_exp2f(st[0]);
  float p1 = __builtin_amdgcn_exp2f(st[1]);
  float p2 = __builtin_amdgcn_exp2f(st[2]);
  float p3 = __builtin_amdgcn_exp2f(st[3]);
  if (maskg) {
    int j0 = quad * 4;
    p0 = (j0 + 0 > mcol) ? 0.f : p0;
    p1 = (j0 + 1 > mcol) ? 0.f : p1;
    p2 = (j0 + 2 > mcol) ? 0.f : p2;
    p3 = (j0 + 3 > mcol) ? 0.f : p3;
  }
  // truncate to bf16 (no rounding add): bias cancels against rsum
  uint2 pk;
  pk.x = __builtin_amdgcn_perm(__builtin_bit_cast(u32, p1),
                               __builtin_bit_cast(u32, p0), 0x07060302u);
  pk.y = __builtin_amdgcn_perm(__builtin_bit_cast(u32, p3),
                               __builtin_bit_cast(u32, p2), 0x07060302u);
  s16x4 pf = __builtin_bit_cast(s16x4, pk);
  const s16x4 ones = {0x3F80, 0x3F80, 0x3F80, 0x3F80};  // bf16 1.0 x4
  __builtin_amdgcn_s_setprio(1);
  S.racc = mfma16b(ones, pf, S.racc);
  S.o0 = mfma16b(vf0, pf, S.o0);
  S.o1 = mfma16b(vf1, pf, S.o1);
  S.o2 = mfma16b(vf2, pf, S.o2);
  S.o3 = mfma16b(vf3, pf, S.o3);
  __builtin_amdgcn_s_setprio(0);
}

#define OSTR 68   // padded f32 row stride for combine staging (bank stagger)

__global__ __launch_bounds__(128) void attn(
    const u16* __restrict__ q, const u16* __restrict__ kg,
    const u16* __restrict__ vg, u16* __restrict__ y)
{
  __shared__ float lds_o[4][16 * OSTR];
  __shared__ float lds_r[64];

  int tid = threadIdx.x;
  int lane = tid & 63, w = tid >> 6;   // w = K-half owner
  int mcol = lane & 15, quad = lane >> 4;
  int gid = blockIdx.x;
  int c = gid & 7;              // XCD (round-robin dispatch heuristic)
  int idx = gid >> 3;           // 0..119
  int sub = idx / 40;           // 0..2  -> 3 bh per XCD (K/V resident in L2)
  int s = idx - sub * 40;       // 0..39
  int bh = c * 3 + sub;
  int hb = s >> 3;              // 0..4  (512-row span)
  int r = s & 7;                // light local strip; heavy local = 7-r
  int b = bh / NH, h = bh - b * NH;
  const u16* qp = q + (size_t)bh * TT * HD;
  const u16* kp = kg + (size_t)bh * TT * HD;
  const u16* vp = vg + (size_t)bh * TT * HD;

  int base = hb * 512;
  int rh = 7 - r;
  int qr[4];
  qr[0] = base + r * 16;              // L1 (half 0 of 256-tile)
  qr[1] = base + 128 + rh * 16;       // H1 (half 1)
  qr[2] = base + 256 + r * 16;        // L2
  qr[3] = base + 384 + rh * 16;       // H2

  Strip S[4];
#pragma unroll
  for (int i = 0; i < 4; ++i) {
    S[i].qf0 = *(const bf16x8*)&qp[(size_t)(qr[i] + mcol) * HD + quad * 8];
    S[i].qf1 = *(const bf16x8*)&qp[(size_t)(qr[i] + mcol) * HD + 32 + quad * 8];
    S[i].o0 = {0.f, 0.f, 0.f, 0.f};
    S[i].o1 = {0.f, 0.f, 0.f, 0.f};
    S[i].o2 = {0.f, 0.f, 0.f, 0.f};
    S[i].o3 = {0.f, 0.f, 0.f, 0.f};
    S[i].racc = {0.f, 0.f, 0.f, 0.f};
  }

  int koff = mcol * 32 + quad * 8;  // u16 offset in K group (b128, coalesced)
  int voff = mcol * 16 + quad * 4;  // u16 offset in V df-slab (b64, coalesced)

  for (int kt = w * 10; kt < w * 10 + 10; ++kt) {
    const u16* ktb = kp + kt * (128 * HD);
    const u16* vtb = vp + kt * (128 * HD);
    if ((kt & 1) == 0) {
      // even tile: heavy strips full 8 groups; light strips groups 0..r
      // depth-2 rotating-register prefetch (~two groups of MFMA cover)
      bf16x8 ck0 = *(const bf16x8*)&ktb[koff];
      bf16x8 ck1 = *(const bf16x8*)&ktb[512 + koff];
      s16x4 cv0 = *(const s16x4*)&vtb[0 * 256 + voff];
      s16x4 cv1 = *(const s16x4*)&vtb[1 * 256 + voff];
      s16x4 cv2 = *(const s16x4*)&vtb[2 * 256 + voff];
      s16x4 cv3 = *(const s16x4*)&vtb[3 * 256 + voff];
      bf16x8 nk0 = *(const bf16x8*)&ktb[1024 + koff];
      bf16x8 nk1 = *(const bf16x8*)&ktb[1024 + 512 + koff];
      s16x4 nv0 = *(const s16x4*)&vtb[1024 + 0 * 256 + voff];
      s16x4 nv1 = *(const s16x4*)&vtb[1024 + 1 * 256 + voff];
      s16x4 nv2 = *(const s16x4*)&vtb[1024 + 2 * 256 + voff];
      s16x4 nv3 = *(const s16x4*)&vtb[1024 + 3 * 256 + voff];
#pragma unroll
      for (int g = 0; g < 8; ++g) {
        bf16x8 pk0, pk1; s16x4 pv0, pv1, pv2, pv3;
        if (g < 6) {
          const u16* kn = ktb + (g + 2) * 1024;
          const u16* vn = vtb + (g + 2) * 1024;
          pk0 = *(const bf16x8*)&kn[koff];
          pk1 = *(const bf16x8*)&kn[512 + koff];
          pv0 = *(const s16x4*)&vn[0 * 256 + voff];
          pv1 = *(const s16x4*)&vn[1 * 256 + voff];
          pv2 = *(const s16x4*)&vn[2 * 256 + voff];
          pv3 = *(const s16x4*)&vn[3 * 256 + voff];
        }
        strip_step(S[1], ck0, ck1, cv0, cv1, cv2, cv3, false, mcol, quad);
        strip_step(S[3], ck0, ck1, cv0, cv1, cv2, cv3, false, mcol, quad);
        if (g <= r) {
          bool mg = (g == r);
          strip_step(S[0], ck0, ck1, cv0, cv1, cv2, cv3, mg, mcol, quad);
          strip_step(S[2], ck0, ck1, cv0, cv1, cv2, cv3, mg, mcol, quad);
        }
        if (g < 7) {
          ck0 = nk0; ck1 = nk1;
          cv0 = nv0; cv1 = nv1; cv2 = nv2; cv3 = nv3;
        }
        if (g < 6) {
          nk0 = pk0; nk1 = pk1;
          nv0 = pv0; nv1 = pv1; nv2 = pv2; nv3 = pv3;
        }
      }
    } else {
      // odd tile: heavy strips groups 0..rh (partial at rh); light strips skip
      // runtime-bound loop -> depth-1 rotating prefetch (clamped last load)
      bf16x8 kf0 = *(const bf16x8*)&ktb[koff];
      bf16x8 kf1 = *(const bf16x8*)&ktb[512 + koff];
      s16x4 vf0 = *(const s16x4*)&vtb[0 * 256 + voff];
      s16x4 vf1 = *(const s16x4*)&vtb[1 * 256 + voff];
      s16x4 vf2 = *(const s16x4*)&vtb[2 * 256 + voff];
      s16x4 vf3 = *(const s16x4*)&vtb[3 * 256 + voff];
      for (int g = 0; g <= rh; ++g) {
        int gn = (g < rh) ? g + 1 : g;
        const u16* kn = ktb + gn * 1024;
        const u16* vn = vtb + gn * 1024;
        bf16x8 nk0 = *(const bf16x8*)&kn[koff];
        bf16x8 nk1 = *(const bf16x8*)&kn[512 + koff];
        s16x4 nv0 = *(const s16x4*)&vn[0 * 256 + voff];
        s16x4 nv1 = *(const s16x4*)&vn[1 * 256 + voff];
        s16x4 nv2 = *(const s16x4*)&vn[2 * 256 + voff];
        s16x4 nv3 = *(const s16x4*)&vn[3 * 256 + voff];
        bool mg = (g == rh);
        strip_step(S[1], kf0, kf1, vf0, vf1, vf2, vf3, mg, mcol, quad);
        strip_step(S[3], kf0, kf1, vf0, vf1, vf2, vf3, mg, mcol, quad);
        kf0 = nk0; kf1 = nk1;
        vf0 = nv0; vf1 = nv1; vf2 = nv2; vf3 = nv3;
      }
    }
  }

  // ---- combine the two K-halves through LDS (partials are additive, m=0) ----
  if (w == 1) {
#pragma unroll
    for (int i = 0; i < 4; ++i) {
      f32x4 oo[4] = {S[i].o0, S[i].o1, S[i].o2, S[i].o3};
#pragma unroll
      for (int df = 0; df < 4; ++df)
        *(f32x4*)&lds_o[i][mcol * OSTR + df * 16 + quad * 4] = oo[df];
      if (quad == 0) lds_r[i * 16 + mcol] = S[i].racc[0];
    }
  }
  __syncthreads();
  if (w == 0) {
#pragma unroll
    for (int i = 0; i < 4; ++i) {
      float denom = S[i].racc[0] + lds_r[i * 16 + mcol];
      float inv = 1.0f / denom;
      f32x4 oo[4] = {S[i].o0, S[i].o1, S[i].o2, S[i].o3};
      size_t yrow = ((size_t)(b * TT + qr[i] + mcol)) * CC + h * HD;
#pragma unroll
      for (int df = 0; df < 4; ++df) {
        f32x4 other = *(const f32x4*)&lds_o[i][mcol * OSTR + df * 16 + quad * 4];
        ushort4 pk;
        pk.x = f2bf((oo[df][0] + other[0]) * inv);
        pk.y = f2bf((oo[df][1] + other[1]) * inv);
        pk.z = f2bf((oo[df][2] + other[2]) * inv);
        pk.w = f2bf((oo[df][3] + other[3]) * inv);
        *(ushort4*)&y[yrow + df * 16 + quad * 4] = pk;
      }
    }
  }
}

// ------- output projection GEMM: 64x128 tile, 480 blocks (r12, validated) ---
// XCD swizzle kept (neutral-to-positive). NO reg-dbuf: r13 spilled
// (VGPR_Count collapsed to 48, WRITE_SIZE 15.5->40MB, dur 25->50us).
// transposed epilogue: acc m-dim = channel, n-dim = token -> float4 stores
__global__ __launch_bounds__(256) void gemm_out(
    const u16* __restrict__ yb, const u16* __restrict__ wpb,
    const float* __restrict__ bp, float* __restrict__ out)
{
  __shared__ __align__(16) u16 lds_a[64 * 72];    // y tokens
  __shared__ __align__(16) u16 lds_b[128 * 72];   // Wp channels
  int g = blockIdx.x;
  int c = g & 7;          // XCD
  int t = g >> 3;         // 0..59
  int y = (t % 10) * 8 + c;   // 0..79 m-panel; all x of this y on XCD c
  int xg = t / 10;        // 0..5
  int n0 = xg * 128;
  int m0 = y * 64;
  int tid = threadIdx.x;
  int lane = tid & 63, wv_ = tid >> 6;
  int wm = wv_ & 1, wn = wv_ >> 1;
  int mcol = lane & 15, quad = lane >> 4;
  int chunk = tid & 7, rbase = tid >> 3;

  f32x4 acc[2][4] = {};

  for (int k0 = 0; k0 < KDIM; k0 += 64) {
    __syncthreads();
#pragma unroll
    for (int r = 0; r < 2; ++r) {
      int row = rbase + r * 32;
      *(uint4*)&lds_a[row * 72 + chunk * 8] =
          *(const uint4*)&yb[(size_t)(m0 + row) * KDIM + k0 + chunk * 8];
    }
#pragma unroll
    for (int r = 0; r < 4; ++r) {
      int row = rbase + r * 32;
      *(uint4*)&lds_b[row * 72 + chunk * 8] =
          *(const uint4*)&wpb[(size_t)(n0 + row) * KDIM + k0 + chunk * 8];
    }
    __syncthreads();
#pragma unroll
    for (int kc = 0; kc < 2; ++kc) {
      bf16x8 af[2], bfr[4];
#pragma unroll
      for (int i = 0; i < 2; i++)
        af[i] = *(const bf16x8*)&lds_a[(wm * 32 + i * 16 + mcol) * 72 + kc * 32 + quad * 8];
#pragma unroll
      for (int j = 0; j < 4; j++)
        bfr[j] = *(const bf16x8*)&lds_b[(wn * 64 + j * 16 + mcol) * 72 + kc * 32 + quad * 8];
#pragma unroll
      for (int i = 0; i < 2; i++)
#pragma unroll
        for (int j = 0; j < 4; j++)
          acc[i][j] = __builtin_amdgcn_mfma_f32_16x16x32_bf16(bfr[j], af[i], acc[i][j], 0, 0, 0);
    }
  }

#pragma unroll
  for (int i = 0; i < 2; i++) {
    int token = m0 + wm * 32 + i * 16 + mcol;
#pragma unroll
    for (int j = 0; j < 4; j++) {
      int ch0 = n0 + wn * 64 + j * 16 + quad * 4;
      float4 bb4 = *(const float4*)&bp[ch0];
      float4 o4;
      o4.x = acc[i][j][0] + bb4.x;
      o4.y = acc[i][j][1] + bb4.y;
      o4.z = acc[i][j][2] + bb4.z;
      o4.w = acc[i][j][3] + bb4.w;
      *(float4*)&out[(size_t)token * CC + ch0] = o4;
    }
  }
}

extern "C" void kernel_launch(void* const* d_in, const int* in_sizes, int n_in,
                              void* d_out, int out_size, void* d_ws, size_t ws_size,
                              hipStream_t stream) {
  const float* x  = (const float*)d_in[0];
  const float* Wk = (const float*)d_in[1];
  const float* bk = (const float*)d_in[2];
  const float* Wq = (const float*)d_in[3];
  const float* bq = (const float*)d_in[4];
  const float* Wv = (const float*)d_in[5];
  const float* bv = (const float*)d_in[6];
  const float* Wp = (const float*)d_in[7];
  const float* bp = (const float*)d_in[8];
  float* out = (float*)d_out;

  char* ws = (char*)d_ws;
  size_t off = 0;
  auto alloc = [&](size_t bytes) {
    void* p = ws + off;
    off += (bytes + 255) & ~(size_t)255;
    return p;
  };
  const size_t NX = (size_t)2 * TT * CC;
  const size_t NW = (size_t)CC * CC;
  u16* xb  = (u16*)alloc(NX * 2);
  u16* wqb = (u16*)alloc(NW * 2);
  u16* wkb = (u16*)alloc(NW * 2);
  u16* wvb = (u16*)alloc(NW * 2);
  u16* wpb = (u16*)alloc(NW * 2);
  u16* qws = (u16*)alloc(NX * 2);
  u16* kws = (u16*)alloc(NX * 2);
  u16* vgw = (u16*)alloc(NX * 2);
  u16* yws = (u16*)alloc(NX * 2);

  int nx4 = (int)(NX / 4), nw4 = (int)(NW / 4);
  convall<<<dim3((nx4 + 255) / 256, 5), 256, 0, stream>>>(
      x, Wq, Wk, Wv, Wp, xb, wqb, wkb, wvb, wpb, nx4, nw4);

  gemm_qkv<<<dim3(720), 256, 0, stream>>>(xb, wqb, wkb, wvb, bq, bk, bv,
                                          qws, kws, vgw);
  attn<<<dim3(960), 128, 0, stream>>>(qws, kws, vgw, yws);
  gemm_out<<<dim3(480), 256, 0, stream>>>(yws, wpb, bp, out);
}